// Round 8
// baseline (585.675 us; speedup 1.0000x reference)
//
#include <hip/hip_runtime.h>
#include <hip/hip_bf16.h>

#define FEAT 256
#define HDIM 256
#define CDIM 64
#define THETA 0.5f
#define APAD 264  // A-tile LDS row stride in bf16 elems (256 + 8 -> +16B pad per row)

typedef float floatx2 __attribute__((ext_vector_type(2)));
typedef __attribute__((ext_vector_type(8))) short bf16x8;
typedef __attribute__((ext_vector_type(4))) float f32x4;

// ---------------- degree ----------------
__global__ __launch_bounds__(256) void deg_count(const int* __restrict__ e0, int E, int* deg) {
    int i = blockIdx.x * 256 + threadIdx.x;
    if (i < E) atomicAdd(&deg[e0[i]], 1);
}

__global__ __launch_bounds__(256) void make_dinv(const int* __restrict__ deg, float* __restrict__ dinv, int N) {
    int i = blockIdx.x * 256 + threadIdx.x;
    if (i < N) dinv[i] = rsqrtf((float)(deg[i] + 1));  // +1 self loop
}

// ---------------- single-block exclusive scan -> rowptr, cursor ----------------
__global__ __launch_bounds__(256) void scan_rowptr(const int* __restrict__ deg,
                                                   int* __restrict__ rowptr,
                                                   int* __restrict__ cursor, int N) {
    __shared__ int part[256];
    const int tid = threadIdx.x;
    const int chunk = (N + 255) / 256;
    const int s = tid * chunk;
    const int e = min(s + chunk, N);
    int sum = 0;
    for (int i = s; i < e; ++i) sum += deg[i];
    part[tid] = sum;
    __syncthreads();
#pragma unroll
    for (int off = 1; off < 256; off <<= 1) {
        int t = (tid >= off) ? part[tid - off] : 0;
        __syncthreads();
        part[tid] += t;
        __syncthreads();
    }
    int run = part[tid] - sum;  // exclusive prefix
    for (int i = s; i < e; ++i) {
        rowptr[i] = run;
        cursor[i] = run;
        run += deg[i];
    }
    if (tid == 255) rowptr[N] = run;
}

// ---------------- bucket edges into CSR ----------------
__global__ __launch_bounds__(256) void bucket_edges(const int* __restrict__ e0,
                                                    const int* __restrict__ e1,
                                                    int* cursor, int* __restrict__ colIdx, int E) {
    int i = blockIdx.x * 256 + threadIdx.x;
    if (i < E) {
        int r = e0[i];
        int pos = atomicAdd(&cursor[r], 1);
        colIdx[pos] = e1[i];
    }
}

// ---------------- conversions ----------------
__device__ __forceinline__ unsigned short f2bf(float f) {
    unsigned int u = __float_as_uint(f);
    u += 0x7fffu + ((u >> 16) & 1u);
    return (unsigned short)(u >> 16);
}
__device__ __forceinline__ float bfl(unsigned int u) { return __uint_as_float(u << 16); }
__device__ __forceinline__ float bfh(unsigned int u) { return __uint_as_float(u & 0xffff0000u); }
__device__ __forceinline__ unsigned char f2f8(float f) {
    int w = __builtin_amdgcn_cvt_pk_fp8_f32(f, f, 0, false);
    return (unsigned char)(w & 0xff);
}

__global__ __launch_bounds__(256) void to_fp8(const float* __restrict__ src,
                                              unsigned char* __restrict__ dst, int n8) {
    int i = blockIdx.x * 256 + threadIdx.x;  // one thread per 8 floats
    if (i >= n8) return;
    float4 a = ((const float4*)src)[2 * i];
    float4 b = ((const float4*)src)[2 * i + 1];
    int w0 = __builtin_amdgcn_cvt_pk_fp8_f32(a.x, a.y, 0, false);
    w0 = __builtin_amdgcn_cvt_pk_fp8_f32(a.z, a.w, w0, true);
    int w1 = __builtin_amdgcn_cvt_pk_fp8_f32(b.x, b.y, 0, false);
    w1 = __builtin_amdgcn_cvt_pk_fp8_f32(b.z, b.w, w1, true);
    uint2 o;
    o.x = (unsigned int)w0;
    o.y = (unsigned int)w1;
    ((uint2*)dst)[i] = o;
}

// ---------------- W[256][256] fp32 -> Wt[n][k] bf16 ----------------
__global__ __launch_bounds__(256) void transposeW(const float* __restrict__ W,
                                                  unsigned short* __restrict__ Wt) {
    int k = blockIdx.x;
    int n = threadIdx.x;
    Wt[(size_t)n * 256 + k] = f2bf(W[(size_t)k * 256 + n]);
}

// ---------------- Wy[256][64] fp32 -> WyT[64][256] bf16 ----------------
__global__ __launch_bounds__(64) void transposeWy(const float* __restrict__ W,
                                                  unsigned short* __restrict__ Wt) {
    int k = blockIdx.x;   // 0..255
    int n = threadIdx.x;  // 0..63
    Wt[(size_t)n * 256 + k] = f2bf(W[(size_t)k * 64 + n]);
}

// ---------------- MFMA core (shared by both A-type GEMMs); emits fp8 h-table ----------------
__device__ __forceinline__ void gemm_core_f8out(const unsigned short* Al,
                                                const unsigned short* __restrict__ Wt,
                                                unsigned char* __restrict__ out,
                                                int m0, int wv, int lane, int M) {
    f32x4 acc[4][4] = {};
    const int r16 = lane & 15;
    const int kg8 = (lane >> 4) * 8;
    const unsigned short* wbase = Wt + ((size_t)(wv * 64 + r16)) * 256 + kg8;
    const unsigned short* abase = Al + r16 * APAD + kg8;

#pragma unroll
    for (int k0 = 0; k0 < 256; k0 += 32) {
        bf16x8 af[4], bfr[4];
#pragma unroll
        for (int mi = 0; mi < 4; ++mi)
            af[mi] = *(const bf16x8*)&abase[mi * 16 * APAD + k0];
#pragma unroll
        for (int ni = 0; ni < 4; ++ni)
            bfr[ni] = *(const bf16x8*)&wbase[ni * 16 * 256 + k0];
#pragma unroll
        for (int mi = 0; mi < 4; ++mi)
#pragma unroll
            for (int ni = 0; ni < 4; ++ni)
                acc[mi][ni] = __builtin_amdgcn_mfma_f32_16x16x32_bf16(af[mi], bfr[ni], acc[mi][ni], 0, 0, 0);
    }

    // epilogue: C/D layout col=lane&15, row=(lane>>4)*4+j
#pragma unroll
    for (int mi = 0; mi < 4; ++mi) {
        int rbase = m0 + mi * 16 + ((lane >> 4) << 2);
#pragma unroll
        for (int ni = 0; ni < 4; ++ni) {
            int col = (wv << 6) + (ni << 4) + (lane & 15);
#pragma unroll
            for (int j = 0; j < 4; ++j) {
                int row = rbase + j;
                if (row < M) out[(size_t)row * 256 + col] = f2f8(acc[mi][ni][j]);
            }
        }
    }
}

// conv1: A fp32 -> h8 fp8
__global__ __launch_bounds__(256) void gemm_mfma_f32A(const float* __restrict__ A,
                                                      const unsigned short* __restrict__ Wt,
                                                      unsigned char* __restrict__ out, int M) {
    __shared__ unsigned short Al[64 * APAD];
    const int tid = threadIdx.x;
    const int m0 = blockIdx.x * 64;
#pragma unroll
    for (int i = 0; i < 8; ++i) {
        int u = i * 256 + tid;
        int r = u >> 5;
        int c8 = (u & 31) * 8;
        int row = m0 + r;
        float4 v0, v1;
        if (row < M) {
            v0 = *(const float4*)&A[(size_t)row * 256 + c8];
            v1 = *(const float4*)&A[(size_t)row * 256 + c8 + 4];
        } else {
            v0 = make_float4(0.f, 0.f, 0.f, 0.f);
            v1 = v0;
        }
        uint4 o;
        o.x = (unsigned int)f2bf(v0.x) | ((unsigned int)f2bf(v0.y) << 16);
        o.y = (unsigned int)f2bf(v0.z) | ((unsigned int)f2bf(v0.w) << 16);
        o.z = (unsigned int)f2bf(v1.x) | ((unsigned int)f2bf(v1.y) << 16);
        o.w = (unsigned int)f2bf(v1.z) | ((unsigned int)f2bf(v1.w) << 16);
        *(uint4*)&Al[r * APAD + c8] = o;
    }
    __syncthreads();
    gemm_core_f8out(Al, Wt, out, m0, tid >> 6, tid & 63, M);
}

// conv2: A bf16 -> h8 fp8
__global__ __launch_bounds__(256) void gemm_mfma_b16A(const unsigned short* __restrict__ A,
                                                      const unsigned short* __restrict__ Wt,
                                                      unsigned char* __restrict__ out, int M) {
    __shared__ unsigned short Al[64 * APAD];
    const int tid = threadIdx.x;
    const int m0 = blockIdx.x * 64;
#pragma unroll
    for (int i = 0; i < 8; ++i) {
        int u = i * 256 + tid;
        int r = u >> 5;
        int c8 = (u & 31) * 8;
        int row = m0 + r;
        uint4 o = make_uint4(0, 0, 0, 0);
        if (row < M) o = *(const uint4*)&A[(size_t)row * 256 + c8];
        *(uint4*)&Al[r * APAD + c8] = o;
    }
    __syncthreads();
    gemm_core_f8out(Al, Wt, out, m0, tid >> 6, tid & 63, M);
}

// ---------------- MFMA head GEMM: y[M,64] = rep[M,256] @ Wy + by ----------------
__global__ __launch_bounds__(256) void gemm_wy_mfma(const float* __restrict__ A,
                                                    const unsigned short* __restrict__ WyT,
                                                    const float* __restrict__ bias,
                                                    float* __restrict__ out, int M) {
    __shared__ unsigned short Al[64 * APAD];
    const int tid = threadIdx.x;
    const int m0 = blockIdx.x * 64;
    const int wv = tid >> 6;  // wave -> output cols [wv*16, wv*16+16)
    const int lane = tid & 63;

#pragma unroll
    for (int i = 0; i < 8; ++i) {
        int u = i * 256 + tid;
        int r = u >> 5;
        int c8 = (u & 31) * 8;
        int row = m0 + r;
        float4 v0, v1;
        if (row < M) {
            v0 = *(const float4*)&A[(size_t)row * 256 + c8];
            v1 = *(const float4*)&A[(size_t)row * 256 + c8 + 4];
        } else {
            v0 = make_float4(0.f, 0.f, 0.f, 0.f);
            v1 = v0;
        }
        uint4 o;
        o.x = (unsigned int)f2bf(v0.x) | ((unsigned int)f2bf(v0.y) << 16);
        o.y = (unsigned int)f2bf(v0.z) | ((unsigned int)f2bf(v0.w) << 16);
        o.z = (unsigned int)f2bf(v1.x) | ((unsigned int)f2bf(v1.y) << 16);
        o.w = (unsigned int)f2bf(v1.z) | ((unsigned int)f2bf(v1.w) << 16);
        *(uint4*)&Al[r * APAD + c8] = o;
    }
    __syncthreads();

    f32x4 acc[4] = {};
    const int r16 = lane & 15;
    const int kg8 = (lane >> 4) * 8;
    const unsigned short* wbase = WyT + ((size_t)(wv * 16 + r16)) * 256 + kg8;
    const unsigned short* abase = Al + r16 * APAD + kg8;

#pragma unroll
    for (int k0 = 0; k0 < 256; k0 += 32) {
        bf16x8 bfr = *(const bf16x8*)&wbase[k0];
#pragma unroll
        for (int mi = 0; mi < 4; ++mi) {
            bf16x8 af = *(const bf16x8*)&abase[mi * 16 * APAD + k0];
            acc[mi] = __builtin_amdgcn_mfma_f32_16x16x32_bf16(af, bfr, acc[mi], 0, 0, 0);
        }
    }

    int col = (wv << 4) + (lane & 15);
    float bv = bias[col];
#pragma unroll
    for (int mi = 0; mi < 4; ++mi) {
        int rbase = m0 + mi * 16 + ((lane >> 4) << 2);
#pragma unroll
        for (int j = 0; j < 4; ++j) {
            int row = rbase + j;
            if (row < M) out[(size_t)row * 64 + col] = acc[mi][j] + bv;
        }
    }
}

// ---------------- CSR gather SpMM (fp8 h table) fused with finalize ----------------
// DO_NORM=0: out_b16 = bf16(relu(x))   (conv1)
// DO_NORM=1: double-l2norm in-wave; write rep fp32 + rep8 fp8 (conv2, no relu)
template <int DO_NORM>
__global__ __launch_bounds__(256) void spmm_gather_f8(const int* __restrict__ rowptr,
                                                      const int* __restrict__ colIdx,
                                                      const unsigned char* __restrict__ h8,
                                                      const float* __restrict__ dinv,
                                                      const float* __restrict__ bias,
                                                      unsigned short* __restrict__ out_b16,
                                                      float* __restrict__ rep,
                                                      unsigned char* __restrict__ rep8,
                                                      int N) {
    int row = (blockIdx.x * 256 + threadIdx.x) >> 6;
    int lane = threadIdx.x & 63;
    if (row >= N) return;
    int beg = rowptr[row];
    int end = rowptr[row + 1];
    float4 acc = make_float4(0.f, 0.f, 0.f, 0.f);
    int j = beg;
    for (; j + 3 < end; j += 4) {
        int c0 = colIdx[j + 0];
        int c1 = colIdx[j + 1];
        int c2 = colIdx[j + 2];
        int c3 = colIdx[j + 3];
        float w0 = dinv[c0], w1 = dinv[c1], w2 = dinv[c2], w3 = dinv[c3];
        unsigned int u0 = *(const unsigned int*)&h8[(size_t)c0 * 256 + lane * 4];
        unsigned int u1 = *(const unsigned int*)&h8[(size_t)c1 * 256 + lane * 4];
        unsigned int u2 = *(const unsigned int*)&h8[(size_t)c2 * 256 + lane * 4];
        unsigned int u3 = *(const unsigned int*)&h8[(size_t)c3 * 256 + lane * 4];
        floatx2 l0 = __builtin_amdgcn_cvt_pk_f32_fp8((int)u0, false);
        floatx2 h0 = __builtin_amdgcn_cvt_pk_f32_fp8((int)u0, true);
        floatx2 l1 = __builtin_amdgcn_cvt_pk_f32_fp8((int)u1, false);
        floatx2 h1 = __builtin_amdgcn_cvt_pk_f32_fp8((int)u1, true);
        floatx2 l2 = __builtin_amdgcn_cvt_pk_f32_fp8((int)u2, false);
        floatx2 h2 = __builtin_amdgcn_cvt_pk_f32_fp8((int)u2, true);
        floatx2 l3 = __builtin_amdgcn_cvt_pk_f32_fp8((int)u3, false);
        floatx2 h3 = __builtin_amdgcn_cvt_pk_f32_fp8((int)u3, true);
        acc.x = fmaf(w0, l0.x, acc.x); acc.y = fmaf(w0, l0.y, acc.y);
        acc.z = fmaf(w0, h0.x, acc.z); acc.w = fmaf(w0, h0.y, acc.w);
        acc.x = fmaf(w1, l1.x, acc.x); acc.y = fmaf(w1, l1.y, acc.y);
        acc.z = fmaf(w1, h1.x, acc.z); acc.w = fmaf(w1, h1.y, acc.w);
        acc.x = fmaf(w2, l2.x, acc.x); acc.y = fmaf(w2, l2.y, acc.y);
        acc.z = fmaf(w2, h2.x, acc.z); acc.w = fmaf(w2, h2.y, acc.w);
        acc.x = fmaf(w3, l3.x, acc.x); acc.y = fmaf(w3, l3.y, acc.y);
        acc.z = fmaf(w3, h3.x, acc.z); acc.w = fmaf(w3, h3.y, acc.w);
    }
    for (; j < end; ++j) {
        int c = colIdx[j];
        float w = dinv[c];
        unsigned int u = *(const unsigned int*)&h8[(size_t)c * 256 + lane * 4];
        floatx2 lo = __builtin_amdgcn_cvt_pk_f32_fp8((int)u, false);
        floatx2 hi = __builtin_amdgcn_cvt_pk_f32_fp8((int)u, true);
        acc.x = fmaf(w, lo.x, acc.x); acc.y = fmaf(w, lo.y, acc.y);
        acc.z = fmaf(w, hi.x, acc.z); acc.w = fmaf(w, hi.y, acc.w);
    }
    float di = dinv[row];
    float s = di * di;
    unsigned int us = *(const unsigned int*)&h8[(size_t)row * 256 + lane * 4];
    floatx2 slo = __builtin_amdgcn_cvt_pk_f32_fp8((int)us, false);
    floatx2 shi = __builtin_amdgcn_cvt_pk_f32_fp8((int)us, true);
    float4 bv = *(const float4*)&bias[lane * 4];
    float4 r;
    r.x = fmaf(di, acc.x, fmaf(s, slo.x, bv.x));
    r.y = fmaf(di, acc.y, fmaf(s, slo.y, bv.y));
    r.z = fmaf(di, acc.z, fmaf(s, shi.x, bv.z));
    r.w = fmaf(di, acc.w, fmaf(s, shi.y, bv.w));
    if (DO_NORM == 0) {
        r.x = fmaxf(r.x, 0.f);
        r.y = fmaxf(r.y, 0.f);
        r.z = fmaxf(r.z, 0.f);
        r.w = fmaxf(r.w, 0.f);
        uint2 o;
        o.x = (unsigned int)f2bf(r.x) | ((unsigned int)f2bf(r.y) << 16);
        o.y = (unsigned int)f2bf(r.z) | ((unsigned int)f2bf(r.w) << 16);
        *(uint2*)&out_b16[(size_t)row * 256 + lane * 4] = o;
    } else {
        float ss = r.x * r.x + r.y * r.y + r.z * r.z + r.w * r.w;
#pragma unroll
        for (int o = 1; o < 64; o <<= 1) ss += __shfl_xor(ss, o);
        float inv = 1.0f / fmaxf(sqrtf(ss), 1e-12f);
        r.x *= inv; r.y *= inv; r.z *= inv; r.w *= inv;
        float ss2 = r.x * r.x + r.y * r.y + r.z * r.z + r.w * r.w;
#pragma unroll
        for (int o = 1; o < 64; o <<= 1) ss2 += __shfl_xor(ss2, o);
        float inv2 = 1.0f / fmaxf(sqrtf(ss2), 1e-12f);
        r.x *= inv2; r.y *= inv2; r.z *= inv2; r.w *= inv2;
        *(float4*)&rep[(size_t)row * 256 + lane * 4] = r;
        int w = __builtin_amdgcn_cvt_pk_fp8_f32(r.x, r.y, 0, false);
        w = __builtin_amdgcn_cvt_pk_fp8_f32(r.z, r.w, w, true);
        *(unsigned int*)&rep8[(size_t)row * 256 + lane * 4] = (unsigned int)w;
    }
}

// ---------------- loss helpers ----------------
__device__ __forceinline__ float dot16fp8(uint4 x, uint4 y) {
    float s = 0.f;
    const unsigned int xs[4] = {x.x, x.y, x.z, x.w};
    const unsigned int ys[4] = {y.x, y.y, y.z, y.w};
#pragma unroll
    for (int i = 0; i < 4; ++i) {
        floatx2 xl = __builtin_amdgcn_cvt_pk_f32_fp8((int)xs[i], false);
        floatx2 xh = __builtin_amdgcn_cvt_pk_f32_fp8((int)xs[i], true);
        floatx2 yl = __builtin_amdgcn_cvt_pk_f32_fp8((int)ys[i], false);
        floatx2 yh = __builtin_amdgcn_cvt_pk_f32_fp8((int)ys[i], true);
        s += xl.x * yl.x + xl.y * yl.y + xh.x * yh.x + xh.y * yh.y;
    }
    return s;
}

// ---------------- reconstruction loss: one edge-pair per THREAD (full row per lane) ----------------
__global__ __launch_bounds__(256) void loss_kernel(const int* __restrict__ e0,
                                                   const int* __restrict__ e1,
                                                   const int* __restrict__ n0,
                                                   const int* __restrict__ n1,
                                                   const unsigned char* __restrict__ rep8,
                                                   const unsigned char* __restrict__ feat8,
                                                   const float* __restrict__ ls,
                                                   float* accum, int E) {
    const int tid = threadIdx.x;
    const int idx = blockIdx.x * 256 + tid;
    const int stride = gridDim.x * 256;
    float ap = 0.f, an = 0.f, cp = 0.f, cn = 0.f;
    for (int e = idx; e < E; e += stride) {
        int a = e0[e], b = e1[e];
        int c = n0[e], d = n1[e];
        if (a < b) {
            const uint4* pra = (const uint4*)&rep8[(size_t)a * 256];
            const uint4* prb = (const uint4*)&rep8[(size_t)b * 256];
            const uint4* pfa = (const uint4*)&feat8[(size_t)a * 256];
            const uint4* pfb = (const uint4*)&feat8[(size_t)b * 256];
            float dp = 0.f, df = 0.f;
#pragma unroll
            for (int i = 0; i < 16; i += 4) {
                uint4 x0 = pra[i + 0], y0 = prb[i + 0];
                uint4 x1 = pra[i + 1], y1 = prb[i + 1];
                uint4 x2 = pra[i + 2], y2 = prb[i + 2];
                uint4 x3 = pra[i + 3], y3 = prb[i + 3];
                dp += dot16fp8(x0, y0) + dot16fp8(x1, y1) + dot16fp8(x2, y2) + dot16fp8(x3, y3);
            }
#pragma unroll
            for (int i = 0; i < 16; i += 4) {
                uint4 x0 = pfa[i + 0], y0 = pfb[i + 0];
                uint4 x1 = pfa[i + 1], y1 = pfb[i + 1];
                uint4 x2 = pfa[i + 2], y2 = pfb[i + 2];
                uint4 x3 = pfa[i + 3], y3 = pfb[i + 3];
                df += dot16fp8(x0, y0) + dot16fp8(x1, y1) + dot16fp8(x2, y2) + dot16fp8(x3, y3);
            }
            float pw = fmaxf(dp, 0.f);
            float pos = THETA * df + (1.0f - THETA) * pw;
            float t = pos - ls[e];
            ap += t * t;
            cp += 1.f;
        }
        if (c < d) {
            const uint4* prc = (const uint4*)&rep8[(size_t)c * 256];
            const uint4* prd = (const uint4*)&rep8[(size_t)d * 256];
            float dn = 0.f;
#pragma unroll
            for (int i = 0; i < 16; i += 4) {
                uint4 x0 = prc[i + 0], y0 = prd[i + 0];
                uint4 x1 = prc[i + 1], y1 = prd[i + 1];
                uint4 x2 = prc[i + 2], y2 = prd[i + 2];
                uint4 x3 = prc[i + 3], y3 = prd[i + 3];
                dn += dot16fp8(x0, y0) + dot16fp8(x1, y1) + dot16fp8(x2, y2) + dot16fp8(x3, y3);
            }
            float nwt = fmaxf(dn, 0.f);
            an += nwt * nwt;
            cn += 1.f;
        }
    }
    // wave reduce
#pragma unroll
    for (int o = 1; o < 64; o <<= 1) {
        ap += __shfl_xor(ap, o);
        an += __shfl_xor(an, o);
        cp += __shfl_xor(cp, o);
        cn += __shfl_xor(cn, o);
    }
    __shared__ float s[4][4];
    const int wline = tid >> 6;
    if ((tid & 63) == 0) {
        s[wline][0] = ap;
        s[wline][1] = an;
        s[wline][2] = cp;
        s[wline][3] = cn;
    }
    __syncthreads();
    if (tid == 0) {
        float tp = 0.f, tn = 0.f, tcp = 0.f, tcn = 0.f;
#pragma unroll
        for (int w = 0; w < 4; ++w) {
            tp += s[w][0];
            tn += s[w][1];
            tcp += s[w][2];
            tcn += s[w][3];
        }
        unsafeAtomicAdd(&accum[0], tp);
        unsafeAtomicAdd(&accum[1], tn);
        unsafeAtomicAdd(&accum[2], tcp);
        unsafeAtomicAdd(&accum[3], tcn);
    }
}

__global__ void loss_final(const float* __restrict__ accum, float* __restrict__ out, int N) {
    out[0] = (accum[1] + accum[0]) * (float)N / (accum[3] + accum[2]);
}

// ---------------- launcher ----------------
extern "C" void kernel_launch(void* const* d_in, const int* in_sizes, int n_in,
                              void* d_out, int out_size, void* d_ws, size_t ws_size,
                              hipStream_t stream) {
    const int* edge = (const int*)d_in[0];
    const float* features = (const float*)d_in[1];
    const float* ls = (const float*)d_in[2];
    const int* nedge = (const int*)d_in[3];
    const float* W1 = (const float*)d_in[4];
    const float* b1 = (const float*)d_in[5];
    const float* W2 = (const float*)d_in[6];
    const float* b2 = (const float*)d_in[7];
    const float* Wy = (const float*)d_in[8];
    const float* by = (const float*)d_in[9];

    const int E = in_sizes[0] / 2;
    const int N = in_sizes[1] / FEAT;
    const int* e0 = edge;
    const int* e1 = edge + E;
    const int* n0 = nedge;
    const int* n1 = nedge + E;

    float* rep = (float*)d_out;          // [N,256]
    float* rec = rep + (size_t)N * 256;  // scalar
    float* y = rec + 1;                  // [N,64], 4B-aligned only

    // workspace carve-out
    char* base = (char*)d_ws;
    size_t off = 0;
    auto carve = [&](size_t bytes) -> void* {
        void* p = base + off;
        off += (bytes + 1023) & ~(size_t)1023;
        return p;
    };
    int* deg = (int*)carve((size_t)N * 4);
    float* dinv = (float*)carve((size_t)N * 4);
    float* accum = (float*)carve(16);
    int* rowptr = (int*)carve((size_t)(N + 1) * 4);
    int* cursor = (int*)carve((size_t)N * 4);
    int* colIdx = (int*)carve((size_t)E * 4);
    unsigned char* h8 = (unsigned char*)carve((size_t)N * 256);         // fp8 h table
    unsigned short* x1B = (unsigned short*)carve((size_t)N * 256 * 2);  // bf16 x1
    unsigned char* feat8 = (unsigned char*)carve((size_t)N * 256);
    unsigned char* rep8 = (unsigned char*)carve((size_t)N * 256);
    unsigned short* Wt1 = (unsigned short*)carve(256 * 256 * 2);
    unsigned short* Wt2 = (unsigned short*)carve(256 * 256 * 2);
    unsigned short* WyT = (unsigned short*)carve(64 * 256 * 2);

    // CSR build
    hipMemsetAsync(deg, 0, (size_t)N * 4, stream);
    deg_count<<<(E + 255) / 256, 256, 0, stream>>>(e0, E, deg);
    make_dinv<<<(N + 255) / 256, 256, 0, stream>>>(deg, dinv, N);
    scan_rowptr<<<1, 256, 0, stream>>>(deg, rowptr, cursor, N);
    bucket_edges<<<(E + 255) / 256, 256, 0, stream>>>(e0, e1, cursor, colIdx, E);

    const int gblk = (N + 63) / 64;
    const int wblk = (N + 3) / 4;
    const int n8 = N * 256 / 8;

    // loss-side fp8 feature table; bf16-transposed weights
    to_fp8<<<(n8 + 255) / 256, 256, 0, stream>>>(features, feat8, n8);
    transposeW<<<256, 256, 0, stream>>>(W1, Wt1);
    transposeW<<<256, 256, 0, stream>>>(W2, Wt2);
    transposeWy<<<256, 64, 0, stream>>>(Wy, WyT);

    // conv1: h8 = fp8(features @ W1); x1B = bf16(relu(gather + selfloop + b1))
    gemm_mfma_f32A<<<gblk, 256, 0, stream>>>(features, Wt1, h8, N);
    spmm_gather_f8<0><<<wblk, 256, 0, stream>>>(rowptr, colIdx, h8, dinv, b1, x1B, nullptr, nullptr, N);

    // conv2: h8 = fp8(x1B @ W2); fused gather + selfloop + b2 + double-l2norm -> rep fp32 + rep8
    gemm_mfma_b16A<<<gblk, 256, 0, stream>>>(x1B, Wt2, h8, N);
    spmm_gather_f8<1><<<wblk, 256, 0, stream>>>(rowptr, colIdx, h8, dinv, b2, nullptr, rep, rep8, N);

    // y = rep @ Wy + by (MFMA)
    gemm_wy_mfma<<<gblk, 256, 0, stream>>>(rep, WyT, by, y, N);

    // loss
    hipMemsetAsync(accum, 0, 16, stream);
    loss_kernel<<<2048, 256, 0, stream>>>(e0, e1, n0, n1, rep8, feat8, ls, accum, E);
    loss_final<<<1, 1, 0, stream>>>(accum, rec, N);
}